// Round 5
// baseline (46586.554 us; speedup 1.0000x reference)
//
#include <hip/hip_runtime.h>
#include <hip/hip_bf16.h>
#include <stdint.h>

// Bidirectional GRU decoder: B=64, S=512, D=H=512, L=2.
// R3 post-mortem: per-step __threadfence() pairs (L2 wbl2/inv walks, ~512/step)
// were the 31 us/step cost. This version has NO fences in the scan loop:
// h lives in an fp32 double-buffer accessed only via relaxed agent-scope atomics
// (sc1: L2-bypass, write-through to Infinity Cache = coherence point).
// Barrier = flag array, relaxed sc1 store + poll; ordering via __syncthreads'
// implicit vmcnt(0) drain before s_barrier.

#define S_LEN 512
#define NCOL 3072
#define M_ROWS 32768
#define NBLK 256

typedef __attribute__((ext_vector_type(4))) float f32x4;
typedef __attribute__((ext_vector_type(8))) short s16x8;

// ---------------- prep kernels ----------------

// Xbf[(t*64+b)*512 + d] = bf16(input[b][t][d])   (t-major rows so scan reads GI contiguously)
__global__ void convert_x_kernel(const float* __restrict__ in, __hip_bfloat16* __restrict__ xbf) {
  int idx = blockIdx.x * 256 + threadIdx.x;       // 16,777,216 total
  int d = idx & 511;
  int m = idx >> 9;
  int b = m & 63, t = m >> 6;
  xbf[idx] = __float2bfloat16(in[((size_t)b * S_LEN + t) * 512 + d]);
}

// WI blocks: 0=W_ih_f[0], 1=W_ih_b[0] feature-reversed, 2=W_ih_f[1], 3=W_ih_b[1]; each [1536][512] bf16
__global__ void convert_wi_kernel(const float* __restrict__ wf, const float* __restrict__ wb,
                                  __hip_bfloat16* __restrict__ wo) {
  int idx = blockIdx.x * 256 + threadIdx.x;       // 3,145,728 total
  int k = idx & 511;
  int row = idx >> 9;                              // 0..6143
  int blk = row / 1536;
  int j = row - blk * 1536;
  float v;
  if (blk == 0)      v = wf[(size_t)j * 512 + k];
  else if (blk == 1) v = wb[(size_t)j * 512 + (511 - k)];   // xb = x[:, ::-1] folded into weights
  else if (blk == 2) v = wf[(size_t)(1536 + j) * 512 + k];
  else               v = wb[(size_t)(1536 + j) * 512 + k];
  wo[idx] = __float2bfloat16(v);
}

// hbbF[dir][pp=0][b][k] = encoder_h[b][dir*512+k]   (fp32)
__global__ void hinit_kernel(const float* __restrict__ enc, float* __restrict__ hbbF) {
  int idx = blockIdx.x * 256 + threadIdx.x;       // 65,536 total
  int k = idx & 511;
  int bb = (idx >> 9) & 63;
  int dir = idx >> 15;
  hbbF[(size_t)dir * 2 * 64 * 512 + (size_t)bb * 512 + k] = enc[(size_t)bb * 1024 + dir * 512 + k];
}

// ---------------- GI GEMM: C[m][col0+n] = sum_k A[m][k]*W[n][k] + bias[n] ----------------
// A: [32768][512] bf16, W: [1536][512] bf16 (B^T form), C: [32768][3072] bf16.
// 128x128 tile, BK=32, 4 waves, 16x16x32 bf16 MFMA, simple reg-staged LDS.
__global__ __launch_bounds__(256) void gemm_bt_bias(
    const __hip_bfloat16* __restrict__ A,
    const __hip_bfloat16* __restrict__ W,
    const float* __restrict__ bias,
    __hip_bfloat16* __restrict__ C,
    int col0) {
  __shared__ __hip_bfloat16 As[128 * 32];
  __shared__ __hip_bfloat16 Ws[128 * 32];
  const int tid = threadIdx.x;
  const int lane = tid & 63;
  const int w = tid >> 6;
  const int bn = blockIdx.x * 128;
  const int bm = blockIdx.y * 128;
  const int wm = (w >> 1) * 64, wn = (w & 1) * 64;
  const int r16 = lane & 15;
  const int koff = (lane >> 4) * 8;

  f32x4 acc[4][4];
#pragma unroll
  for (int i = 0; i < 4; ++i)
#pragma unroll
    for (int j = 0; j < 4; ++j) acc[i][j] = (f32x4){0.f, 0.f, 0.f, 0.f};

  for (int kt = 0; kt < 512; kt += 32) {
    __syncthreads();   // protect LDS from previous iteration's readers
#pragma unroll
    for (int i = 0; i < 2; ++i) {
      int seg = i * 256 + tid;                  // 0..511, 16B segments
      int row = seg >> 2, cs = seg & 3;
      *(s16x8*)&As[seg * 8] = *(const s16x8*)(A + ((size_t)(bm + row) << 9) + kt + cs * 8);
      *(s16x8*)&Ws[seg * 8] = *(const s16x8*)(W + ((size_t)(bn + row) << 9) + kt + cs * 8);
    }
    __syncthreads();
    s16x8 af[4], wfr[4];
#pragma unroll
    for (int i = 0; i < 4; ++i) {
      af[i]  = *(const s16x8*)&As[(wm + i * 16 + r16) * 32 + koff];
      wfr[i] = *(const s16x8*)&Ws[(wn + i * 16 + r16) * 32 + koff];
    }
#pragma unroll
    for (int i = 0; i < 4; ++i)
#pragma unroll
      for (int j = 0; j < 4; ++j)
        acc[i][j] = __builtin_amdgcn_mfma_f32_16x16x32_bf16(af[i], wfr[j], acc[i][j], 0, 0, 0);
  }

  const int rq = (lane >> 4) * 4;
#pragma unroll
  for (int j = 0; j < 4; ++j) {
    int n = bn + wn + j * 16 + r16;
    float bv = bias[n];
#pragma unroll
    for (int i = 0; i < 4; ++i) {
#pragma unroll
      for (int q = 0; q < 4; ++q) {
        int m = bm + wm + i * 16 + rq + q;
        C[(size_t)m * NCOL + col0 + n] = __float2bfloat16(acc[i][j][q] + bv);
      }
    }
  }
}

// ---------------- persistent scan ----------------
// 256 blocks x 512 threads, 1 block/CU. block: dir = bid>>7, hidden cols j4..j4+3.
// threads: b = tid&63, kseg = tid>>6. W_hh slice resident in LDS all 512 steps.
// h: fp32 double-buffer in ws, ALL accesses relaxed agent atomics (sc1 bypass).
// No __threadfence anywhere: __syncthreads' vmcnt(0) drain orders h stores
// before the flag store; sc1 loads can't see stale L1/L2.
__global__ __launch_bounds__(512) void scan_kernel(
    const float* __restrict__ Whf, const float* __restrict__ Whb,   // [1536][512] this layer
    const float* __restrict__ bhf, const float* __restrict__ bhb,   // [1536]
    const __hip_bfloat16* __restrict__ GI,                           // [32768][3072]
    __hip_bfloat16* __restrict__ X1f, __hip_bfloat16* __restrict__ X1b,
    float* out, float* out2,
    float* hbbF,                                                     // [2][2][64][512] fp32
    int* arrive, int gen_base, int last) {
  __shared__ float Wlds[12][512];     // 24 KB
  __shared__ float bh_lds[12];
  __shared__ float red[8][64][12];    // 24 KB

  const int tid = threadIdx.x;
  const int bid = blockIdx.x;
  const int dir = bid >> 7;
  const int j4 = (bid & 127) * 4;
  const float* Wsrc = dir ? Whb : Whf;
  const float* bhsrc = dir ? bhb : bhf;

  for (int idx = tid; idx < 12 * 512; idx += 512) {
    int c = idx >> 9, k = idx & 511;
    int jc = c / 3, g = c - jc * 3;
    Wlds[c][k] = Wsrc[((size_t)(g * 512 + j4 + jc) << 9) + k];
  }
  if (tid < 12) {
    int jc = tid / 3, g = tid - jc * 3;
    bh_lds[tid] = bhsrc[g * 512 + j4 + jc];
  }
  __syncthreads();

  const int b = tid & 63;
  const int kseg = tid >> 6;
  float* hd = hbbF + (size_t)dir * 2 * 64 * 512;

  for (int t = 0; t < S_LEN; ++t) {
    const int pp = t & 1;
    // ---- load h[b][kseg*64..+63]: 64 relaxed agent (sc1) loads, pipelined ----
    const float* hrow = hd + (size_t)pp * 32768 + (size_t)b * 512 + kseg * 64;
    float hreg[64];
#pragma unroll
    for (int i = 0; i < 64; ++i)
      hreg[i] = __hip_atomic_load(&hrow[i], __ATOMIC_RELAXED, __HIP_MEMORY_SCOPE_AGENT);
    // ---- 12 partial dot products over this k-segment (W reads are wave-uniform broadcasts) ----
    float acc[12];
#pragma unroll
    for (int c = 0; c < 12; ++c) acc[c] = 0.f;
#pragma unroll
    for (int c = 0; c < 12; ++c) {
      const float* wrow = &Wlds[c][kseg * 64];
#pragma unroll
      for (int k4 = 0; k4 < 16; ++k4) {
        f32x4 wv = *(const f32x4*)(wrow + k4 * 4);
        acc[c] += hreg[k4 * 4 + 0] * wv.x + hreg[k4 * 4 + 1] * wv.y +
                  hreg[k4 * 4 + 2] * wv.z + hreg[k4 * 4 + 3] * wv.w;
      }
    }
    *(f32x4*)&red[kseg][b][0] = (f32x4){acc[0], acc[1], acc[2], acc[3]};
    *(f32x4*)&red[kseg][b][4] = (f32x4){acc[4], acc[5], acc[6], acc[7]};
    *(f32x4*)&red[kseg][b][8] = (f32x4){acc[8], acc[9], acc[10], acc[11]};
    __syncthreads();

    // ---- gates: threads 0..255 = (b, jc) ----
    if (tid < 256) {
      const int jc = tid >> 6;
      const int j = j4 + jc;
      // prefetch h_old early (sc1, ~coherence-point latency)
      float hold = __hip_atomic_load(&hd[(size_t)pp * 32768 + (size_t)b * 512 + j],
                                     __ATOMIC_RELAXED, __HIP_MEMORY_SCOPE_AGENT);
      float gr = 0.f, gz = 0.f, gn2 = 0.f;
#pragma unroll
      for (int ks = 0; ks < 8; ++ks) {
        gr  += red[ks][b][jc * 3 + 0];
        gz  += red[ks][b][jc * 3 + 1];
        gn2 += red[ks][b][jc * 3 + 2];
      }
      const size_t m = (size_t)t * 64 + b;
      const __hip_bfloat16* gi = GI + m * NCOL + dir * 1536;
      float ir = __bfloat162float(gi[j]);
      float iz = __bfloat162float(gi[512 + j]);
      float in_ = __bfloat162float(gi[1024 + j]);
      float r = 1.f / (1.f + __expf(-(ir + gr + bh_lds[jc * 3 + 0])));
      float z = 1.f / (1.f + __expf(-(iz + gz + bh_lds[jc * 3 + 1])));
      float hn = gn2 + bh_lds[jc * 3 + 2];
      float x2 = 2.f * (in_ + r * hn);
      float n = 1.f - 2.f / (1.f + __expf(x2));       // tanh via exp
      float hnew = (1.f - z) * n + z * hold;
      __hip_atomic_store(&hd[(size_t)(pp ^ 1) * 32768 + (size_t)b * 512 + j], hnew,
                         __ATOMIC_RELAXED, __HIP_MEMORY_SCOPE_AGENT);
      if (!last) {
        (dir ? X1b : X1f)[m * 512 + j] = __float2bfloat16(hnew);
      } else {
        out[((size_t)b * 512 + t) * 1024 + dir * 512 + j] = hnew;
        if (t == S_LEN - 1) out2[(size_t)b * 1024 + dir * 512 + j] = hnew;
      }
    }

    // ---- flag-array grid barrier, fence-free ----
    // __syncthreads drains vmcnt(0) in every thread => all sc1 h-stores are at the
    // coherence point before the flag store below becomes visible.
    __syncthreads();
    const int target = gen_base + t + 1;
    if (tid == 0)
      __hip_atomic_store(&arrive[bid], target, __ATOMIC_RELAXED, __HIP_MEMORY_SCOPE_AGENT);
    if (tid < 64) {
      for (;;) {
        int v0 = __hip_atomic_load(&arrive[tid],       __ATOMIC_RELAXED, __HIP_MEMORY_SCOPE_AGENT);
        int v1 = __hip_atomic_load(&arrive[tid + 64],  __ATOMIC_RELAXED, __HIP_MEMORY_SCOPE_AGENT);
        int v2 = __hip_atomic_load(&arrive[tid + 128], __ATOMIC_RELAXED, __HIP_MEMORY_SCOPE_AGENT);
        int v3 = __hip_atomic_load(&arrive[tid + 192], __ATOMIC_RELAXED, __HIP_MEMORY_SCOPE_AGENT);
        bool ok = (v0 >= target) & (v1 >= target) & (v2 >= target) & (v3 >= target);
        if (__all(ok)) break;
        __builtin_amdgcn_s_sleep(1);
      }
    }
    __syncthreads();
  }
}

// ---------------- launch ----------------
extern "C" void kernel_launch(void* const* d_in, const int* in_sizes, int n_in,
                              void* d_out, int out_size, void* d_ws, size_t ws_size,
                              hipStream_t stream) {
  (void)in_sizes; (void)n_in; (void)out_size; (void)ws_size;
  const float* input = (const float*)d_in[0];
  const float* enc_h = (const float*)d_in[2];
  const float* Wihf  = (const float*)d_in[3];
  const float* Whhf  = (const float*)d_in[4];
  const float* bihf  = (const float*)d_in[5];
  const float* bhhf  = (const float*)d_in[6];
  const float* Wihb  = (const float*)d_in[7];
  const float* Whhb  = (const float*)d_in[8];
  const float* bihb  = (const float*)d_in[9];
  const float* bhhb  = (const float*)d_in[10];

  float* out  = (float*)d_out;
  float* out2 = out + (size_t)M_ROWS * 1024;

  char* ws = (char*)d_ws;
  int* arrive = (int*)ws;                                       // 4 KB
  float* hbbF = (float*)(ws + 4096);                            // 512 KB fp32 h dbuf
  __hip_bfloat16* Xbf = (__hip_bfloat16*)(ws + 528384);         // 32 MB
  __hip_bfloat16* WI  = (__hip_bfloat16*)(ws + 34082816ull);    // 6 MB
  __hip_bfloat16* GI  = (__hip_bfloat16*)(ws + 40374272ull);    // 192 MB
  // X1 (layer-0 outputs, bf16) overlaid into d_out: fully rewritten by layer-1 scan afterwards.
  __hip_bfloat16* X1f = (__hip_bfloat16*)d_out;
  __hip_bfloat16* X1b = X1f + (size_t)M_ROWS * 512;

  hipMemsetAsync(ws, 0, 4096, stream);
  convert_x_kernel<<<65536, 256, 0, stream>>>(input, Xbf);
  convert_wi_kernel<<<12288, 256, 0, stream>>>(Wihf, Wihb, WI);
  hinit_kernel<<<256, 256, 0, stream>>>(enc_h, hbbF);

  dim3 gg(12, 256);
  gemm_bt_bias<<<gg, 256, 0, stream>>>(Xbf, WI,               bihf,        GI, 0);
  gemm_bt_bias<<<gg, 256, 0, stream>>>(Xbf, WI + 786432,      bihb,        GI, 1536);
  scan_kernel<<<NBLK, 512, 0, stream>>>(Whhf, Whhb, bhhf, bhhb, GI, X1f, X1b,
                                        out, out2, hbbF, arrive, 0, 0);
  gemm_bt_bias<<<gg, 256, 0, stream>>>(X1f, WI + 2 * 786432,  bihf + 1536, GI, 0);
  gemm_bt_bias<<<gg, 256, 0, stream>>>(X1b, WI + 3 * 786432,  bihb + 1536, GI, 1536);
  hinit_kernel<<<256, 256, 0, stream>>>(enc_h, hbbF);
  scan_kernel<<<NBLK, 512, 0, stream>>>(Whhf + 786432, Whhb + 786432, bhhf + 1536, bhhb + 1536,
                                        GI, X1f, X1b, out, out2, hbbF, arrive, 512, 1);
}